// Round 3
// baseline (562.284 us; speedup 1.0000x reference)
//
#include <hip/hip_runtime.h>
#include <hip/hip_bf16.h>
#include <math.h>

namespace {

constexpr int B  = 4;
constexpr int N  = 2048;
constexpr int F0 = 6;
constexpr int F  = 64;
constexpr int DK = 16;
constexpr float EPS = 1e-5f;
constexpr int NCH0 = 16;  // n-chunks, layer-0 adjacency
constexpr int MT   = N / 64;  // m-tiles for big layers

// ---------------- squared norms per node ----------------
template<int D>
__global__ __launch_bounds__(256) void k_sqnorm(const float* __restrict__ x,
                                                float* __restrict__ sqn) {
  int idx = blockIdx.x * 256 + threadIdx.x;
  if (idx >= B * N) return;
  int b = idx >> 11;
  int n = idx & (N - 1);
  const float* xp = x + (size_t)b * D * N + n;
  float s = 0.f;
#pragma unroll
  for (int d = 0; d < D; ++d) { float v = xp[(size_t)d * N]; s = fmaf(v, v, s); }
  sqn[idx] = s;
}

// ---------------- layer-0 fused adjacency + deg + adj_msg (D=F=6) ----------------
__global__ __launch_bounds__(256) void k_adj0(const float* __restrict__ x,
                                              const float* __restrict__ sqn,
                                              const float* __restrict__ sigma,
                                              float* __restrict__ pdmsg,  // (NCH0,B,F0,N)
                                              float* __restrict__ pdeg) { // (NCH0,B,N)
  constexpr int NC = N / NCH0;  // 128
  int t = threadIdx.x;
  int m = blockIdx.x * 256 + t;
  int ch = blockIdx.y, b = blockIdx.z;
  float sg = sigma[0];
  float inv_s2 = 1.f / (sg * sg);
  const float* xb = x + (size_t)b * F0 * N;
  float pm[F0];
#pragma unroll
  for (int d = 0; d < F0; ++d) pm[d] = xb[(size_t)d * N + m];
  float sqm = sqn[b * N + m];
  float acc[F0] = {};
  float deg = 0.f;
  // [nn][d0..5, 6=sqnorm, 7 pad] -> per-nn reads are two broadcast b128
  __shared__ __align__(16) float xt[64][8];
  int n0 = ch * NC;
  for (int nt = 0; nt < NC; nt += 64) {
    __syncthreads();
    for (int e = t; e < F0 * 64; e += 256) {
      int d = e >> 6, nn = e & 63;
      xt[nn][d] = xb[(size_t)d * N + n0 + nt + nn];
    }
    if (t < 64) xt[t][6] = sqn[b * N + n0 + nt + t];
    __syncthreads();
#pragma unroll 2
    for (int nn = 0; nn < 64; ++nn) {
      float4 p0 = *(const float4*)&xt[nn][0];
      float4 p1 = *(const float4*)&xt[nn][4];
      float g = fmaf(pm[0], p0.x, 0.f);
      g = fmaf(pm[1], p0.y, g);
      g = fmaf(pm[2], p0.z, g);
      g = fmaf(pm[3], p0.w, g);
      g = fmaf(pm[4], p1.x, g);
      g = fmaf(pm[5], p1.y, g);
      float dist = fmaxf(sqm + p1.z - 2.f * g, 0.f);
      float a = __expf(-dist * inv_s2);
      deg += a;
      acc[0] = fmaf(a, p0.x, acc[0]);
      acc[1] = fmaf(a, p0.y, acc[1]);
      acc[2] = fmaf(a, p0.z, acc[2]);
      acc[3] = fmaf(a, p0.w, acc[3]);
      acc[4] = fmaf(a, p1.x, acc[4]);
      acc[5] = fmaf(a, p1.y, acc[5]);
    }
  }
  size_t base = (size_t)ch * B + b;
#pragma unroll
  for (int d = 0; d < F0; ++d) pdmsg[(base * F0 + d) * N + m] = acc[d];
  pdeg[base * N + m] = deg;
}

// ---------------- big-layer fused adjacency + deg + adj_msg (D=16, F=64) ----------------
// 1-D grid, XCD-aware swizzle: all m-tiles of one (ch,b) combo land on one XCD
// so the V/proj chunk stays L2-resident (fix for the 100MB/dispatch L2 thrash).
__global__ __launch_bounds__(256, 3) void k_adjmsg(const float* __restrict__ proj,
                                                   const float* __restrict__ sqn,
                                                   const float* __restrict__ V,
                                                   float* __restrict__ pdmsg,  // (nch,B,F,N)
                                                   float* __restrict__ pdeg,   // (nch,B,N)
                                                   int nch, int cpx) {         // cpx = nch*B/8
  constexpr int D = DK;
  const int NCb = N / nch;
  int i = blockIdx.x;
  int xcd = i & 7;            // dispatch round-robins XCDs
  int j = i >> 3;
  int lc = j / MT;
  int mtile = j - lc * MT;
  int combo = xcd * cpx + lc; // 0..nch*B-1, bijective
  int ch = combo >> 2;        // /B
  int b  = combo & 3;
  int M0 = mtile * 64;
  int n0 = ch * NCb;

  int t = threadIdx.x;
  int tm = t & 15, tf = t >> 4;
  int m4 = tm * 4, f4 = tf * 4, n4 = tf * 4;
  const float* pb = proj + (size_t)b * D * N;
  const float* vb = V + (size_t)b * F * N;
  const float* sq = sqn + (size_t)b * N;

  __shared__ __align__(16) float pnS[D][64];
  __shared__ float sqnS[64];
  __shared__ __align__(16) float adjS[64][68];  // pad 68: 2-way-max banks
  __shared__ __align__(16) float vtS[64][68];
  __shared__ float degW[4][64];

  // m-tile operand in registers (64 VGPR) + norms
  float pmr[D][4];
#pragma unroll
  for (int d = 0; d < D; ++d)
    *(float4*)pmr[d] = *(const float4*)&pb[(size_t)d * N + M0 + m4];
  float sqmr[4];
  *(float4*)sqmr = *(const float4*)&sq[M0 + m4];

  float acc[4][4] = {};
  float pd[4] = {};

  for (int nt = 0; nt < NCb; nt += 64) {
    __syncthreads();
    {  // stage proj n-tile (256 float4, one per thread)
      int d = t >> 4, nq = (t & 15) * 4;
      *(float4*)&pnS[d][nq] = *(const float4*)&pb[(size_t)d * N + n0 + nt + nq];
    }
    if (t < 64) sqnS[t] = sq[n0 + nt + t];
#pragma unroll
    for (int r = 0; r < 4; ++r) {  // stage V transposed
      int e = r * 256 + t;
      int f = e >> 4, nq = (e & 15) * 4;
      float4 v4 = *(const float4*)&vb[(size_t)f * N + n0 + nt + nq];
      vtS[nq + 0][f] = v4.x;
      vtS[nq + 1][f] = v4.y;
      vtS[nq + 2][f] = v4.z;
      vtS[nq + 3][f] = v4.w;
    }
    __syncthreads();
    // gram 4x4 + exp -> adj tile
    float g[4][4] = {};
#pragma unroll 4
    for (int d = 0; d < D; ++d) {
      float bn[4];
      *(float4*)bn = *(const float4*)&pnS[d][n4];
#pragma unroll
      for (int jj = 0; jj < 4; ++jj)
#pragma unroll
        for (int k = 0; k < 4; ++k) g[jj][k] = fmaf(pmr[d][jj], bn[k], g[jj][k]);
    }
#pragma unroll
    for (int k = 0; k < 4; ++k) {
      float row[4];
#pragma unroll
      for (int jj = 0; jj < 4; ++jj) {
        float dist = fmaxf(sqmr[jj] + sqnS[n4 + k] - 2.f * g[jj][k], 0.f);
        float a = __expf(-dist);
        row[jj] = a;
        pd[jj] += a;
      }
      *(float4*)&adjS[n4 + k][m4] = *(float4*)row;
    }
    __syncthreads();
    // PV: acc[i][j] += sum_n vt[n][f4+i] * adj[n][m4+j]  (both reads b128)
#pragma unroll 8
    for (int n = 0; n < 64; ++n) {
      float aa[4], vv[4];
      *(float4*)aa = *(const float4*)&adjS[n][m4];
      *(float4*)vv = *(const float4*)&vtS[n][f4];
#pragma unroll
      for (int jj = 0; jj < 4; ++jj) {
        acc[0][jj] = fmaf(vv[0], aa[jj], acc[0][jj]);
        acc[1][jj] = fmaf(vv[1], aa[jj], acc[1][jj]);
        acc[2][jj] = fmaf(vv[2], aa[jj], acc[2][jj]);
        acc[3][jj] = fmaf(vv[3], aa[jj], acc[3][jj]);
      }
    }
  }
  // deg: butterfly over the 4 same-tm lanes in wave, then cross-wave via LDS
#pragma unroll
  for (int jj = 0; jj < 4; ++jj) {
    pd[jj] += __shfl_xor(pd[jj], 16);
    pd[jj] += __shfl_xor(pd[jj], 32);
  }
  if ((t & 63) < 16) {
#pragma unroll
    for (int jj = 0; jj < 4; ++jj) degW[t >> 6][m4 + jj] = pd[jj];
  }
  __syncthreads();
  if (t < 64) {
    float s = degW[0][t] + degW[1][t] + degW[2][t] + degW[3][t];
    pdeg[((size_t)combo) * N + M0 + t] = s;
  }
  float* pdm = pdmsg + (size_t)combo * F * N;
#pragma unroll
  for (int i2 = 0; i2 < 4; ++i2) {
    *(float4*)&pdm[(size_t)(f4 + i2) * N + M0 + m4] =
        make_float4(acc[i2][0], acc[i2][1], acc[i2][2], acc[i2][3]);
  }
}

// ---------------- chunk-combine + gopconv epilogue ----------------
template<int FIN>
__global__ __launch_bounds__(256) void k_gopconv(const float* __restrict__ X,
                                                 const float* __restrict__ pdmsg,
                                                 const float* __restrict__ pdeg,
                                                 const float* __restrict__ W,     // (64,2*FIN)
                                                 const float* __restrict__ bias,  // (64)
                                                 const float* __restrict__ Wres,  // (64,FIN)
                                                 const float* __restrict__ bres,  // (64)
                                                 float* __restrict__ out,         // (B,64,N)
                                                 int nch) {
  int t = threadIdx.x;
  int m = blockIdx.x * 64 + (t & 63);
  int og = __builtin_amdgcn_readfirstlane(t >> 6);  // wave-uniform -> scalar W loads
  int b = blockIdx.y;
  float deg = 0.f;
  for (int c = 0; c < nch; ++c) deg += pdeg[((size_t)c * B + b) * N + m];
  float cacc[16], racc[16];
#pragma unroll
  for (int k = 0; k < 16; ++k) {
    cacc[k] = bias[og * 16 + k];
    racc[k] = bres[og * 16 + k];
  }
  for (int f = 0; f < FIN; ++f) {
    float x = X[((size_t)b * FIN + f) * N + m];
    float dm = 0.f;
    for (int c = 0; c < nch; ++c) dm += pdmsg[(((size_t)c * B + b) * FIN + f) * N + m];
    float c0 = x * deg;
#pragma unroll
    for (int k = 0; k < 16; ++k) {
      int o = og * 16 + k;
      cacc[k] = fmaf(W[(size_t)o * 2 * FIN + f], c0, cacc[k]);
      cacc[k] = fmaf(W[(size_t)o * 2 * FIN + FIN + f], dm, cacc[k]);
      racc[k] = fmaf(Wres[(size_t)o * FIN + f], x, racc[k]);
    }
  }
#pragma unroll
  for (int k = 0; k < 16; ++k) {
    out[((size_t)b * F + og * 16 + k) * N + m] = fmaxf(cacc[k], 0.f) + racc[k];
  }
}

// ---------------- fused spatialnorm: stats + normalize, one block per (b,f) row ----------------
__global__ __launch_bounds__(256) void k_norm(const float* __restrict__ emb,
                                              float* __restrict__ Vout) {
  int row = blockIdx.x;  // b*F + f
  int t = threadIdx.x;
  const float4* p = (const float4*)(emb + (size_t)row * N);
  float4* o = (float4*)(Vout + (size_t)row * N);
  __shared__ __align__(16) float4 buf[N / 4];  // 8KB
  float s = 0.f, s2 = 0.f;
#pragma unroll
  for (int i = t; i < N / 4; i += 256) {
    float4 v = p[i];
    buf[i] = v;
    s += v.x + v.y + v.z + v.w;
    s2 = fmaf(v.x, v.x, s2); s2 = fmaf(v.y, v.y, s2);
    s2 = fmaf(v.z, v.z, s2); s2 = fmaf(v.w, v.w, s2);
  }
#pragma unroll
  for (int off = 1; off < 64; off <<= 1) {
    s += __shfl_xor(s, off);
    s2 += __shfl_xor(s2, off);
  }
  __shared__ float rs[4], rq[4], stat[2];
  if ((t & 63) == 0) { rs[t >> 6] = s; rq[t >> 6] = s2; }
  __syncthreads();
  if (t == 0) {
    float S = rs[0] + rs[1] + rs[2] + rs[3];
    float Q = rq[0] + rq[1] + rq[2] + rq[3];
    float mn = S / N;
    float var = Q / N - mn * mn;
    stat[0] = mn;
    stat[1] = rsqrtf(var + EPS);
  }
  __syncthreads();
  float mn = stat[0], r = stat[1];
#pragma unroll
  for (int i = t; i < N / 4; i += 256) {
    float4 v = buf[i];
    o[i] = make_float4((v.x - mn) * r, (v.y - mn) * r, (v.z - mn) * r, (v.w - mn) * r);
  }
}

// ---------------- fused proj = adj_proj[i] @ emb  +  sqnorm(proj) ----------------
__global__ __launch_bounds__(256) void k_proj_sq(const float* __restrict__ ap,   // (DK,F)
                                                 const float* __restrict__ emb,  // (B,F,N)
                                                 float* __restrict__ proj,       // (B,DK,N)
                                                 float* __restrict__ sqn) {      // (B,N)
  int t = threadIdx.x;
  int b = blockIdx.y;
  int n = blockIdx.x * 64 + (t & 63);
  int dg = __builtin_amdgcn_readfirstlane(t >> 6);  // wave-uniform d-group
  const float* e = emb + (size_t)b * F * N + n;
  float acc[4] = {0.f, 0.f, 0.f, 0.f};
  for (int f = 0; f < F; ++f) {
    float x = e[(size_t)f * N];
#pragma unroll
    for (int q = 0; q < 4; ++q) acc[q] = fmaf(ap[(dg * 4 + q) * F + f], x, acc[q]);
  }
  float s = 0.f;
#pragma unroll
  for (int q = 0; q < 4; ++q) {
    proj[((size_t)b * DK + dg * 4 + q) * N + n] = acc[q];
    s = fmaf(acc[q], acc[q], s);
  }
  __shared__ float sp[4][64];
  sp[dg][t & 63] = s;
  __syncthreads();
  if (t < 64) sqn[(size_t)b * N + blockIdx.x * 64 + t] =
      sp[0][t] + sp[1][t] + sp[2][t] + sp[3][t];
}

// ---------------- readout: pool + instance-norm + fcl + sigmoid ----------------
__global__ __launch_bounds__(256) void k_readout(const float* __restrict__ emb,
                                                 const float* __restrict__ fw,
                                                 const float* __restrict__ fb,
                                                 float* __restrict__ out) {
  int b = blockIdx.x, t = threadIdx.x;
  int f = t & 63, part = t >> 6;
  const float* p = emb + ((size_t)b * F + f) * N;
  float s = 0.f;
  for (int i = part * (N / 4); i < (part + 1) * (N / 4); ++i) s += p[i];
  __shared__ float red[4][64];
  red[part][f] = s;
  __syncthreads();
  if (t == 0) {
    float pooled[64];
    float mn = 0.f;
    for (int q = 0; q < 64; ++q) {
      float po = (red[0][q] + red[1][q] + red[2][q] + red[3][q]) / (float)N;
      pooled[q] = po;
      mn += po;
    }
    mn /= 64.f;
    float var = 0.f;
    for (int q = 0; q < 64; ++q) {
      float d2 = pooled[q] - mn;
      var = fmaf(d2, d2, var);
    }
    var /= 64.f;
    float r = rsqrtf(var + EPS);
    float lg = fb[0];
    for (int q = 0; q < 64; ++q) lg = fmaf((pooled[q] - mn) * r, fw[q], lg);
    out[b] = 1.f / (1.f + __expf(-lg));
  }
}

}  // namespace

extern "C" void kernel_launch(void* const* d_in, const int* in_sizes, int n_in,
                              void* d_out, int out_size, void* d_ws, size_t ws_size,
                              hipStream_t stream) {
  const float* emb_in   = (const float*)d_in[0];
  const float* sigma    = (const float*)d_in[1];
  const float* fst_w    = (const float*)d_in[2];
  const float* fst_b    = (const float*)d_in[3];
  const float* fst_wres = (const float*)d_in[4];
  const float* fst_bres = (const float*)d_in[5];
  const float* adj_proj = (const float*)d_in[6];
  const float* w        = (const float*)d_in[7];
  const float* bw       = (const float*)d_in[8];
  const float* wres     = (const float*)d_in[9];
  const float* bres     = (const float*)d_in[10];
  const float* fcl_w    = (const float*)d_in[11];
  const float* fcl_b    = (const float*)d_in[12];

  // runtime chunk count for big layers, gated on workspace size
  auto need_bytes = [](int nch) -> size_t {
    size_t f = 0;
    f += B * N;                                   // sqn
    f += (size_t)((nch > NCH0) ? nch : NCH0) * B * N;  // pdeg
    size_t pd1 = (size_t)nch * B * F * N, pd0 = (size_t)NCH0 * B * F0 * N;
    f += (pd1 > pd0) ? pd1 : pd0;                 // pdmsg
    f += 3 * (size_t)B * F * N;                   // embA, embB, Vb
    f += (size_t)B * DK * N;                      // projb
    return f * 4;
  };
  int nch = (ws_size >= need_bytes(8)) ? 8 : 4;
  int cpx = nch * B / 8;

  float* ws = (float*)d_ws;
  float* sqn   = ws;  ws += B * N;
  float* pdeg  = ws;  ws += (size_t)((nch > NCH0) ? nch : NCH0) * B * N;
  size_t pd1 = (size_t)nch * B * F * N, pd0 = (size_t)NCH0 * B * F0 * N;
  float* pdmsg = ws;  ws += (pd1 > pd0) ? pd1 : pd0;
  float* embA  = ws;  ws += (size_t)B * F * N;
  float* embB  = ws;  ws += (size_t)B * F * N;
  float* Vb    = ws;  ws += (size_t)B * F * N;
  float* projb = ws;  ws += (size_t)B * DK * N;

  // ---- layer 0 (input adjacency with sigma) ----
  k_sqnorm<F0><<<dim3(B * N / 256), 256, 0, stream>>>(emb_in, sqn);
  k_adj0<<<dim3(N / 256, NCH0, B), 256, 0, stream>>>(emb_in, sqn, sigma, pdmsg, pdeg);
  k_gopconv<F0><<<dim3(N / 64, B), 256, 0, stream>>>(
      emb_in, pdmsg, pdeg, fst_w, fst_b, fst_wres, fst_bres, embA, NCH0);

  // ---- layers 1..2 (learned adjacency) ----
  const float* src = embA;
  float* dst = embB;
  for (int i = 0; i < 2; ++i) {
    k_proj_sq<<<dim3(N / 64, B), 256, 0, stream>>>(adj_proj + (size_t)i * DK * F, src,
                                                   projb, sqn);
    k_norm<<<dim3(B * F), 256, 0, stream>>>(src, Vb);
    k_adjmsg<<<dim3(MT * nch * B), 256, 0, stream>>>(projb, sqn, Vb, pdmsg, pdeg, nch, cpx);
    k_gopconv<F><<<dim3(N / 64, B), 256, 0, stream>>>(
        Vb, pdmsg, pdeg, w + (size_t)i * F * 2 * F, bw + (size_t)i * F,
        wres + (size_t)i * F * F, bres + (size_t)i * F, dst, nch);
    float* tmp = (float*)src;
    src = dst;
    dst = tmp;
  }

  k_readout<<<dim3(B), 256, 0, stream>>>(src, fcl_w, fcl_b, (float*)d_out);
}

// Round 4
// 306.488 us; speedup vs baseline: 1.8346x; 1.8346x over previous
//
#include <hip/hip_runtime.h>
#include <hip/hip_bf16.h>
#include <math.h>

namespace {

constexpr int B  = 4;
constexpr int N  = 2048;
constexpr int F0 = 6;
constexpr int F  = 64;
constexpr int DK = 16;
constexpr float EPS = 1e-5f;
constexpr int NCH0 = 16;  // n-chunks, layer-0 adjacency
constexpr int MT   = N / 64;  // m-tiles for big layers

// ---------------- squared norms per node ----------------
template<int D>
__global__ __launch_bounds__(256) void k_sqnorm(const float* __restrict__ x,
                                                float* __restrict__ sqn) {
  int idx = blockIdx.x * 256 + threadIdx.x;
  if (idx >= B * N) return;
  int b = idx >> 11;
  int n = idx & (N - 1);
  const float* xp = x + (size_t)b * D * N + n;
  float s = 0.f;
#pragma unroll
  for (int d = 0; d < D; ++d) { float v = xp[(size_t)d * N]; s = fmaf(v, v, s); }
  sqn[idx] = s;
}

// ---------------- layer-0 fused adjacency + deg + adj_msg (D=F=6) ----------------
__global__ __launch_bounds__(256) void k_adj0(const float* __restrict__ x,
                                              const float* __restrict__ sqn,
                                              const float* __restrict__ sigma,
                                              float* __restrict__ pdmsg,  // (NCH0,B,F0,N)
                                              float* __restrict__ pdeg) { // (NCH0,B,N)
  constexpr int NC = N / NCH0;  // 128
  int t = threadIdx.x;
  int m = blockIdx.x * 256 + t;
  int ch = blockIdx.y, b = blockIdx.z;
  float sg = sigma[0];
  float inv_s2 = 1.f / (sg * sg);
  const float* xb = x + (size_t)b * F0 * N;
  float pm[F0];
#pragma unroll
  for (int d = 0; d < F0; ++d) pm[d] = xb[(size_t)d * N + m];
  float sqm = sqn[b * N + m];
  float acc[F0] = {};
  float deg = 0.f;
  // [nn][d0..5, 6=sqnorm, 7 pad] -> per-nn reads are two broadcast b128
  __shared__ __align__(16) float xt[64][8];
  int n0 = ch * NC;
  for (int nt = 0; nt < NC; nt += 64) {
    __syncthreads();
    for (int e = t; e < F0 * 64; e += 256) {
      int d = e >> 6, nn = e & 63;
      xt[nn][d] = xb[(size_t)d * N + n0 + nt + nn];
    }
    if (t < 64) xt[t][6] = sqn[b * N + n0 + nt + t];
    __syncthreads();
#pragma unroll 2
    for (int nn = 0; nn < 64; ++nn) {
      float4 p0 = *(const float4*)&xt[nn][0];
      float4 p1 = *(const float4*)&xt[nn][4];
      float g = fmaf(pm[0], p0.x, 0.f);
      g = fmaf(pm[1], p0.y, g);
      g = fmaf(pm[2], p0.z, g);
      g = fmaf(pm[3], p0.w, g);
      g = fmaf(pm[4], p1.x, g);
      g = fmaf(pm[5], p1.y, g);
      float dist = fmaxf(sqm + p1.z - 2.f * g, 0.f);
      float a = __expf(-dist * inv_s2);
      deg += a;
      acc[0] = fmaf(a, p0.x, acc[0]);
      acc[1] = fmaf(a, p0.y, acc[1]);
      acc[2] = fmaf(a, p0.z, acc[2]);
      acc[3] = fmaf(a, p0.w, acc[3]);
      acc[4] = fmaf(a, p1.x, acc[4]);
      acc[5] = fmaf(a, p1.y, acc[5]);
    }
  }
  size_t base = (size_t)ch * B + b;
#pragma unroll
  for (int d = 0; d < F0; ++d) pdmsg[(base * F0 + d) * N + m] = acc[d];
  pdeg[base * N + m] = deg;
}

// ---------------- big-layer fused adjacency + deg + adj_msg (D=16, F=64) ----------------
// 1-D grid, XCD-aware swizzle: all m-tiles of one (ch,b) combo land on one XCD
// so the V/proj chunk stays L2-resident.
__global__ __launch_bounds__(256, 3) void k_adjmsg(const float* __restrict__ proj,
                                                   const float* __restrict__ sqn,
                                                   const float* __restrict__ V,
                                                   float* __restrict__ pdmsg,  // (nch,B,F,N)
                                                   float* __restrict__ pdeg,   // (nch,B,N)
                                                   int nch, int cpx) {         // cpx = nch*B/8
  constexpr int D = DK;
  const int NCb = N / nch;
  int i = blockIdx.x;
  int xcd = i & 7;            // dispatch round-robins XCDs
  int j = i >> 3;
  int lc = j / MT;
  int mtile = j - lc * MT;
  int combo = xcd * cpx + lc; // 0..nch*B-1, bijective
  int ch = combo >> 2;        // /B
  int b  = combo & 3;
  int M0 = mtile * 64;
  int n0 = ch * NCb;

  int t = threadIdx.x;
  int tm = t & 15, tf = t >> 4;
  int m4 = tm * 4, f4 = tf * 4, n4 = tf * 4;
  const float* pb = proj + (size_t)b * D * N;
  const float* vb = V + (size_t)b * F * N;
  const float* sq = sqn + (size_t)b * N;

  __shared__ __align__(16) float pnS[D][64];
  __shared__ float sqnS[64];
  __shared__ __align__(16) float adjS[64][68];  // pad 68: 2-way-max banks
  __shared__ __align__(16) float vtS[64][68];
  __shared__ float degW[4][64];

  // m-tile operand in registers (64 VGPR) + norms
  float pmr[D][4];
#pragma unroll
  for (int d = 0; d < D; ++d)
    *(float4*)pmr[d] = *(const float4*)&pb[(size_t)d * N + M0 + m4];
  float sqmr[4];
  *(float4*)sqmr = *(const float4*)&sq[M0 + m4];

  float acc[4][4] = {};
  float pd[4] = {};

  for (int nt = 0; nt < NCb; nt += 64) {
    __syncthreads();
    {  // stage proj n-tile (256 float4, one per thread)
      int d = t >> 4, nq = (t & 15) * 4;
      *(float4*)&pnS[d][nq] = *(const float4*)&pb[(size_t)d * N + n0 + nt + nq];
    }
    if (t < 64) sqnS[t] = sq[n0 + nt + t];
#pragma unroll
    for (int r = 0; r < 4; ++r) {  // stage V transposed
      int e = r * 256 + t;
      int f = e >> 4, nq = (e & 15) * 4;
      float4 v4 = *(const float4*)&vb[(size_t)f * N + n0 + nt + nq];
      vtS[nq + 0][f] = v4.x;
      vtS[nq + 1][f] = v4.y;
      vtS[nq + 2][f] = v4.z;
      vtS[nq + 3][f] = v4.w;
    }
    __syncthreads();
    // gram 4x4 + exp -> adj tile
    float g[4][4] = {};
#pragma unroll 4
    for (int d = 0; d < D; ++d) {
      float bn[4];
      *(float4*)bn = *(const float4*)&pnS[d][n4];
#pragma unroll
      for (int jj = 0; jj < 4; ++jj)
#pragma unroll
        for (int k = 0; k < 4; ++k) g[jj][k] = fmaf(pmr[d][jj], bn[k], g[jj][k]);
    }
#pragma unroll
    for (int k = 0; k < 4; ++k) {
      float row[4];
#pragma unroll
      for (int jj = 0; jj < 4; ++jj) {
        float dist = fmaxf(sqmr[jj] + sqnS[n4 + k] - 2.f * g[jj][k], 0.f);
        float a = __expf(-dist);
        row[jj] = a;
        pd[jj] += a;
      }
      *(float4*)&adjS[n4 + k][m4] = *(float4*)row;
    }
    __syncthreads();
    // PV: acc[i][j] += sum_n vt[n][f4+i] * adj[n][m4+j]  (both reads b128)
#pragma unroll 8
    for (int n = 0; n < 64; ++n) {
      float aa[4], vv[4];
      *(float4*)aa = *(const float4*)&adjS[n][m4];
      *(float4*)vv = *(const float4*)&vtS[n][f4];
#pragma unroll
      for (int jj = 0; jj < 4; ++jj) {
        acc[0][jj] = fmaf(vv[0], aa[jj], acc[0][jj]);
        acc[1][jj] = fmaf(vv[1], aa[jj], acc[1][jj]);
        acc[2][jj] = fmaf(vv[2], aa[jj], acc[2][jj]);
        acc[3][jj] = fmaf(vv[3], aa[jj], acc[3][jj]);
      }
    }
  }
  // deg: butterfly over same-tm lanes in wave, then cross-wave via LDS
#pragma unroll
  for (int jj = 0; jj < 4; ++jj) {
    pd[jj] += __shfl_xor(pd[jj], 16);
    pd[jj] += __shfl_xor(pd[jj], 32);
  }
  if ((t & 63) < 16) {
#pragma unroll
    for (int jj = 0; jj < 4; ++jj) degW[t >> 6][m4 + jj] = pd[jj];
  }
  __syncthreads();
  if (t < 64) {
    float s = degW[0][t] + degW[1][t] + degW[2][t] + degW[3][t];
    pdeg[((size_t)combo) * N + M0 + t] = s;
  }
  float* pdm = pdmsg + (size_t)combo * F * N;
#pragma unroll
  for (int i2 = 0; i2 < 4; ++i2) {
    *(float4*)&pdm[(size_t)(f4 + i2) * N + M0 + m4] =
        make_float4(acc[i2][0], acc[i2][1], acc[i2][2], acc[i2][3]);
  }
}

// ---------------- chunk-combine + gopconv epilogue (compile-time NCHt!) ----------------
// NCHt runtime in R3 caused accumulator spill (VGPR=24, 165us). Keep template.
template<int FIN, int NCHt>
__global__ __launch_bounds__(256) void k_gopconv(const float* __restrict__ X,
                                                 const float* __restrict__ pdmsg,
                                                 const float* __restrict__ pdeg,
                                                 const float* __restrict__ W,     // (64,2*FIN)
                                                 const float* __restrict__ bias,  // (64)
                                                 const float* __restrict__ Wres,  // (64,FIN)
                                                 const float* __restrict__ bres,  // (64)
                                                 float* __restrict__ out) {       // (B,64,N)
  int t = threadIdx.x;
  int m = blockIdx.x * 64 + (t & 63);
  int og = __builtin_amdgcn_readfirstlane(t >> 6);  // wave-uniform -> scalar W loads
  int b = blockIdx.y;
  float deg = 0.f;
#pragma unroll
  for (int c = 0; c < NCHt; ++c) deg += pdeg[((size_t)c * B + b) * N + m];
  float cacc[16], racc[16];
#pragma unroll
  for (int k = 0; k < 16; ++k) {
    cacc[k] = bias[og * 16 + k];
    racc[k] = bres[og * 16 + k];
  }
#pragma unroll 2
  for (int f = 0; f < FIN; ++f) {
    float x = X[((size_t)b * FIN + f) * N + m];
    float dm = 0.f;
#pragma unroll
    for (int c = 0; c < NCHt; ++c) dm += pdmsg[(((size_t)c * B + b) * FIN + f) * N + m];
    float c0 = x * deg;
#pragma unroll
    for (int k = 0; k < 16; ++k) {
      int o = og * 16 + k;
      cacc[k] = fmaf(W[(size_t)o * 2 * FIN + f], c0, cacc[k]);
      cacc[k] = fmaf(W[(size_t)o * 2 * FIN + FIN + f], dm, cacc[k]);
      racc[k] = fmaf(Wres[(size_t)o * FIN + f], x, racc[k]);
    }
  }
#pragma unroll
  for (int k = 0; k < 16; ++k) {
    out[((size_t)b * F + og * 16 + k) * N + m] = fmaxf(cacc[k], 0.f) + racc[k];
  }
}

// ---------------- fused spatialnorm: stats + normalize, one block per (b,f) row ----------------
__global__ __launch_bounds__(256) void k_norm(const float* __restrict__ emb,
                                              float* __restrict__ Vout) {
  int row = blockIdx.x;  // b*F + f
  int t = threadIdx.x;
  const float4* p = (const float4*)(emb + (size_t)row * N);
  float4* o = (float4*)(Vout + (size_t)row * N);
  __shared__ __align__(16) float4 buf[N / 4];  // 8KB
  float s = 0.f, s2 = 0.f;
#pragma unroll
  for (int i = t; i < N / 4; i += 256) {
    float4 v = p[i];
    buf[i] = v;
    s += v.x + v.y + v.z + v.w;
    s2 = fmaf(v.x, v.x, s2); s2 = fmaf(v.y, v.y, s2);
    s2 = fmaf(v.z, v.z, s2); s2 = fmaf(v.w, v.w, s2);
  }
#pragma unroll
  for (int off = 1; off < 64; off <<= 1) {
    s += __shfl_xor(s, off);
    s2 += __shfl_xor(s2, off);
  }
  __shared__ float rs[4], rq[4], stat[2];
  if ((t & 63) == 0) { rs[t >> 6] = s; rq[t >> 6] = s2; }
  __syncthreads();
  if (t == 0) {
    float S = rs[0] + rs[1] + rs[2] + rs[3];
    float Q = rq[0] + rq[1] + rq[2] + rq[3];
    float mn = S / N;
    float var = Q / N - mn * mn;
    stat[0] = mn;
    stat[1] = rsqrtf(var + EPS);
  }
  __syncthreads();
  float mn = stat[0], r = stat[1];
#pragma unroll
  for (int i = t; i < N / 4; i += 256) {
    float4 v = buf[i];
    o[i] = make_float4((v.x - mn) * r, (v.y - mn) * r, (v.z - mn) * r, (v.w - mn) * r);
  }
}

// ---------------- fused proj = adj_proj[i] @ emb  +  sqnorm(proj) ----------------
__global__ __launch_bounds__(256) void k_proj_sq(const float* __restrict__ ap,   // (DK,F)
                                                 const float* __restrict__ emb,  // (B,F,N)
                                                 float* __restrict__ proj,       // (B,DK,N)
                                                 float* __restrict__ sqn) {      // (B,N)
  int t = threadIdx.x;
  int b = blockIdx.y;
  int n = blockIdx.x * 64 + (t & 63);
  int dg = __builtin_amdgcn_readfirstlane(t >> 6);  // wave-uniform d-group
  const float* e = emb + (size_t)b * F * N + n;
  float acc[4] = {0.f, 0.f, 0.f, 0.f};
#pragma unroll 4
  for (int f = 0; f < F; ++f) {
    float x = e[(size_t)f * N];
#pragma unroll
    for (int q = 0; q < 4; ++q) acc[q] = fmaf(ap[(dg * 4 + q) * F + f], x, acc[q]);
  }
  float s = 0.f;
#pragma unroll
  for (int q = 0; q < 4; ++q) {
    proj[((size_t)b * DK + dg * 4 + q) * N + n] = acc[q];
    s = fmaf(acc[q], acc[q], s);
  }
  __shared__ float sp[4][64];
  sp[dg][t & 63] = s;
  __syncthreads();
  if (t < 64) sqn[(size_t)b * N + blockIdx.x * 64 + t] =
      sp[0][t] + sp[1][t] + sp[2][t] + sp[3][t];
}

// ---------------- readout: pool + instance-norm + fcl + sigmoid ----------------
__global__ __launch_bounds__(256) void k_readout(const float* __restrict__ emb,
                                                 const float* __restrict__ fw,
                                                 const float* __restrict__ fb,
                                                 float* __restrict__ out) {
  int b = blockIdx.x, t = threadIdx.x;
  int f = t & 63, part = t >> 6;
  const float* p = emb + ((size_t)b * F + f) * N;
  float s = 0.f;
  for (int i = part * (N / 4); i < (part + 1) * (N / 4); ++i) s += p[i];
  __shared__ float red[4][64];
  red[part][f] = s;
  __syncthreads();
  if (t == 0) {
    float pooled[64];
    float mn = 0.f;
    for (int q = 0; q < 64; ++q) {
      float po = (red[0][q] + red[1][q] + red[2][q] + red[3][q]) / (float)N;
      pooled[q] = po;
      mn += po;
    }
    mn /= 64.f;
    float var = 0.f;
    for (int q = 0; q < 64; ++q) {
      float d2 = pooled[q] - mn;
      var = fmaf(d2, d2, var);
    }
    var /= 64.f;
    float r = rsqrtf(var + EPS);
    float lg = fb[0];
    for (int q = 0; q < 64; ++q) lg = fmaf((pooled[q] - mn) * r, fw[q], lg);
    out[b] = 1.f / (1.f + __expf(-lg));
  }
}

}  // namespace

extern "C" void kernel_launch(void* const* d_in, const int* in_sizes, int n_in,
                              void* d_out, int out_size, void* d_ws, size_t ws_size,
                              hipStream_t stream) {
  const float* emb_in   = (const float*)d_in[0];
  const float* sigma    = (const float*)d_in[1];
  const float* fst_w    = (const float*)d_in[2];
  const float* fst_b    = (const float*)d_in[3];
  const float* fst_wres = (const float*)d_in[4];
  const float* fst_bres = (const float*)d_in[5];
  const float* adj_proj = (const float*)d_in[6];
  const float* w        = (const float*)d_in[7];
  const float* bw       = (const float*)d_in[8];
  const float* wres     = (const float*)d_in[9];
  const float* bres     = (const float*)d_in[10];
  const float* fcl_w    = (const float*)d_in[11];
  const float* fcl_b    = (const float*)d_in[12];

  // runtime chunk count for big layers, gated on workspace size
  auto need_bytes = [](int nch) -> size_t {
    size_t f = 0;
    f += B * N;                                        // sqn
    f += (size_t)((nch > NCH0) ? nch : NCH0) * B * N;  // pdeg
    size_t pd1 = (size_t)nch * B * F * N, pd0 = (size_t)NCH0 * B * F0 * N;
    f += (pd1 > pd0) ? pd1 : pd0;                      // pdmsg
    f += 3 * (size_t)B * F * N;                        // embA, embB, Vb
    f += (size_t)B * DK * N;                           // projb
    return f * 4;
  };
  int nch = (ws_size >= need_bytes(8)) ? 8 : 4;
  int cpx = nch * B / 8;

  float* ws = (float*)d_ws;
  float* sqn   = ws;  ws += B * N;
  float* pdeg  = ws;  ws += (size_t)((nch > NCH0) ? nch : NCH0) * B * N;
  size_t pd1 = (size_t)nch * B * F * N, pd0 = (size_t)NCH0 * B * F0 * N;
  float* pdmsg = ws;  ws += (pd1 > pd0) ? pd1 : pd0;
  float* embA  = ws;  ws += (size_t)B * F * N;
  float* embB  = ws;  ws += (size_t)B * F * N;
  float* Vb    = ws;  ws += (size_t)B * F * N;
  float* projb = ws;  ws += (size_t)B * DK * N;

  // ---- layer 0 (input adjacency with sigma) ----
  k_sqnorm<F0><<<dim3(B * N / 256), 256, 0, stream>>>(emb_in, sqn);
  k_adj0<<<dim3(N / 256, NCH0, B), 256, 0, stream>>>(emb_in, sqn, sigma, pdmsg, pdeg);
  k_gopconv<F0, NCH0><<<dim3(N / 64, B), 256, 0, stream>>>(
      emb_in, pdmsg, pdeg, fst_w, fst_b, fst_wres, fst_bres, embA);

  // ---- layers 1..2 (learned adjacency) ----
  const float* src = embA;
  float* dst = embB;
  for (int i = 0; i < 2; ++i) {
    k_proj_sq<<<dim3(N / 64, B), 256, 0, stream>>>(adj_proj + (size_t)i * DK * F, src,
                                                   projb, sqn);
    k_norm<<<dim3(B * F), 256, 0, stream>>>(src, Vb);
    k_adjmsg<<<dim3(MT * nch * B), 256, 0, stream>>>(projb, sqn, Vb, pdmsg, pdeg, nch, cpx);
    if (nch == 8) {
      k_gopconv<F, 8><<<dim3(N / 64, B), 256, 0, stream>>>(
          Vb, pdmsg, pdeg, w + (size_t)i * F * 2 * F, bw + (size_t)i * F,
          wres + (size_t)i * F * F, bres + (size_t)i * F, dst);
    } else {
      k_gopconv<F, 4><<<dim3(N / 64, B), 256, 0, stream>>>(
          Vb, pdmsg, pdeg, w + (size_t)i * F * 2 * F, bw + (size_t)i * F,
          wres + (size_t)i * F * F, bres + (size_t)i * F, dst);
    }
    float* tmp = (float*)src;
    src = dst;
    dst = tmp;
  }

  k_readout<<<dim3(B), 256, 0, stream>>>(src, fcl_w, fcl_b, (float*)d_out);
}